// Round 14
// baseline (83.761 us; speedup 1.0000x reference)
//
#include <hip/hip_runtime.h>

typedef float f32x4 __attribute__((ext_vector_type(4)));

constexpr int EMB    = 300;
constexpr int EMB4   = 75;     // 8-B bf16 chunks per row
constexpr int HIDDEN = 512;
constexpr int SEQ    = 512;
constexpr int BATCH  = 1024;
constexpr int VOCAB  = 50000;
constexpr int NBUK   = 32;     // vocab buckets
constexpr int BDIV   = 1563;   // ceil(50000/32)
constexpr int NX     = 8;      // vocab slots == XCDs (NJ=4 buckets each)
constexpr int TSTR   = 32;     // ticket stride in ints: one 128-B line per slot
constexpr int NQ     = BATCH / 4;   // 256 batch-quads per slot
constexpr int GMLP   = 8;      // batches per mlp block
constexpr int NCONV  = 1792;   // convert blocks inside prep
constexpr int ELEM4  = VOCAB * EMB / 4;   // float4s in emb

__device__ __forceinline__ unsigned short f2bf(float x) {   // RNE f32->bf16
    unsigned u = __float_as_uint(x);
    u += 0x7fffu + ((u >> 16) & 1u);
    return (unsigned short)(u >> 16);
}

__device__ __forceinline__ f32x4 bf4up(uint2 u) {   // 4 bf16 -> f32x4
    f32x4 r;
    r.x = __uint_as_float(u.x << 16);
    r.y = __uint_as_float(u.x & 0xffff0000u);
    r.z = __uint_as_float(u.y << 16);
    r.w = __uint_as_float(u.y & 0xffff0000u);
    return r;
}

// ---------------- Kernel 1: prep = bucketize + f32->bf16 convert + tickets ---
__global__ __launch_bounds__(256) void prep_kernel(
    const int* __restrict__ text,      // [SEQ, BATCH]
    const int* __restrict__ lengths,   // [BATCH]
    const float* __restrict__ emb,     // [VOCAB, EMB]
    int* __restrict__ btok,            // [BATCH, SEQ]
    int* __restrict__ boff,            // [BATCH, NBUK+1]
    unsigned short* __restrict__ ebf,  // [VOCAB, EMB] bf16
    int* __restrict__ tickets,         // [NX*TSTR] padded (1 line/slot)
    int doConv)
{
    __shared__ int4 tstage[SEQ];           // 8 KB
    __shared__ int  hist[4][8][NBUK + 2];

    const int tid = threadIdx.x;

    if (blockIdx.x >= 256) {               // ---- convert lane ----
        if (blockIdx.x == 256 && tid < NX) tickets[tid * TSTR] = 0;  // reset every call
        if (!doConv) return;
        const float4* src = (const float4*)emb;
        ushort4*      dst = (ushort4*)ebf;
        const int gtid = (blockIdx.x - 256) * 256 + tid;
        for (int i = gtid; i < ELEM4; i += NCONV * 256) {
            const float4 v = src[i];
            ushort4 o;
            o.x = f2bf(v.x); o.y = f2bf(v.y);
            o.z = f2bf(v.z); o.w = f2bf(v.w);
            dst[i] = o;
        }
        return;
    }

    // ---- bucketize lane (verified since R9; bitwise-stable output) ----
    const int wave = tid >> 6;
    const int lane = tid & 63;
    const int b0   = blockIdx.x * 4;
    const int b    = b0 + wave;
    const int len  = lengths[b];
    const unsigned long long lt = (1ull << lane) - 1ull;

    for (int s = tid; s < SEQ; s += 256)
        tstage[s] = *(const int4*)&text[(size_t)s * BATCH + b0];
    for (int i = tid; i < 4 * 8 * (NBUK + 2); i += 256)
        ((int*)hist)[i] = 0;
    __syncthreads();

    int tokv[8], kv[8], rkv[8];
#pragma unroll
    for (int c = 0; c < 8; ++c) {
        const int s      = c * 64 + lane;
        const bool valid = s < len;
        const int tok = valid ? ((const int*)&tstage[s])[wave] : 0;
        const int k   = valid ? tok / BDIV : NBUK;
        unsigned long long mm = ~0ull;
#pragma unroll
        for (int bit = 0; bit < 6; ++bit) {
            const unsigned long long bl = __ballot((k >> bit) & 1);
            mm &= ((k >> bit) & 1) ? bl : ~bl;
        }
        const int rk = __popcll(mm & lt);
        tokv[c] = tok; kv[c] = k; rkv[c] = rk;
        if (valid && rk == 0) hist[wave][c][k] = __popcll(mm);
    }
    __syncthreads();

    int tot = 0;
    if (lane < NBUK) {
#pragma unroll
        for (int c = 0; c < 8; ++c) {
            const int t = hist[wave][c][lane];
            hist[wave][c][lane] = tot;
            tot += t;
        }
    }
    int incl = tot;
#pragma unroll
    for (int off = 1; off < 32; off <<= 1) {
        const int v = __shfl_up(incl, off);
        if (lane >= off && lane < NBUK) incl += v;
    }
    const int excl = incl - tot;
    if (lane < NBUK)      boff[b * (NBUK + 1) + lane] = excl;
    if (lane == NBUK - 1) boff[b * (NBUK + 1) + NBUK] = incl;
    __syncthreads();

#pragma unroll
    for (int c = 0; c < 8; ++c) {
        const int s  = c * 64 + lane;
        const int k  = kv[c];
        const int bb = __shfl(excl, k);
        const int pos = bb + hist[wave][c][k] + rkv[c];
        if (s < len) btok[(size_t)b * SEQ + pos] = tokv[c];
    }
}

// ---------------- Kernel 2: pool — XCD-pinned claims (padded tickets) --------
// 2048 blocks x 256 thr (8/CU, all resident). Block reads its PHYSICAL XCD id
// and claims batch-quads from the matching vocab slot's ticket, so slot x's
// 3.75 MB bf16 slice is gathered (almost) only from XCD x's L2. Each ticket
// owns a full 128-B line: claims to different slots never share a line (the
// R11 serialization bug: 14k same-line atomics x 12 ns = 173 us). Blocks ==
// claims (2048), so ~1 claim + ~1 probe per block; the steal sweep (t>0)
// guarantees completeness under any dispatch; claims are unique, values are
// schedule-independent -> deterministic output.
__global__ __launch_bounds__(256) void pool_kernel(
    const int* __restrict__ btok,      // [BATCH, SEQ] bucket-grouped
    const int* __restrict__ boff,      // [BATCH, NBUK+1]
    const unsigned short* __restrict__ ebf, // [VOCAB, EMB] bf16
    float* __restrict__ partial,       // [NX, BATCH, EMB]
    int* __restrict__ tickets)         // [NX*TSTR] padded
{
    __shared__ int toks[4][SEQ];       // 8 KB, wave-private rows
    __shared__ int claimsh;

    int xcc;
    asm volatile("s_getreg_b32 %0, hwreg(HW_REG_XCC_ID)" : "=s"(xcc));
    xcc &= (NX - 1);

    const int wave = threadIdx.x >> 6;
    const int lane = threadIdx.x & 63;
    const int NJ   = NBUK / NX;        // 4 buckets per slot
    const uint2* e2 = (const uint2*)ebf;
    const bool two  = lane < (EMB4 - 64);
    const int  c2   = 64 + lane;

    for (int t = 0; t < NX; ++t) {
        const int x = (xcc + t) & (NX - 1);
        while (true) {
            __syncthreads();
            if (threadIdx.x == 0) claimsh = atomicAdd(&tickets[x * TSTR], 1);
            __syncthreads();
            const int g = claimsh;
            if (g >= NQ) break;

            const int b  = g * 4 + wave;                 // this wave's batch
            const int lo = boff[b * (NBUK + 1) + x * NJ];
            const int hi = boff[b * (NBUK + 1) + x * NJ + NJ];
            const int n  = hi - lo;

            for (int tt = lane; tt < n; tt += 64)
                toks[wave][tt] = btok[(size_t)b * SEQ + lo + tt];
            // no barrier: same-wave LDS ordering handled by lgkmcnt

            f32x4 A = {0.f, 0.f, 0.f, 0.f};
            f32x4 B = A, C = A, D = A;
            int i = 0;
            for (; i + 8 <= n; i += 8) {
                const int4 ta = *(const int4*)&toks[wave][i];
                const int4 tb = *(const int4*)&toks[wave][i + 4];
                const uint2 u0 = e2[(size_t)ta.x * EMB4 + lane];
                const uint2 u1 = e2[(size_t)ta.y * EMB4 + lane];
                const uint2 u2 = e2[(size_t)ta.z * EMB4 + lane];
                const uint2 u3 = e2[(size_t)ta.w * EMB4 + lane];
                const uint2 u4 = e2[(size_t)tb.x * EMB4 + lane];
                const uint2 u5 = e2[(size_t)tb.y * EMB4 + lane];
                const uint2 u6 = e2[(size_t)tb.z * EMB4 + lane];
                const uint2 u7 = e2[(size_t)tb.w * EMB4 + lane];
                A += bf4up(u0) + bf4up(u1);
                B += bf4up(u2) + bf4up(u3);
                A += bf4up(u4) + bf4up(u5);
                B += bf4up(u6) + bf4up(u7);
                if (two) {
                    const uint2 w0 = e2[(size_t)ta.x * EMB4 + c2];
                    const uint2 w1 = e2[(size_t)ta.y * EMB4 + c2];
                    const uint2 w2 = e2[(size_t)ta.z * EMB4 + c2];
                    const uint2 w3 = e2[(size_t)ta.w * EMB4 + c2];
                    const uint2 w4 = e2[(size_t)tb.x * EMB4 + c2];
                    const uint2 w5 = e2[(size_t)tb.y * EMB4 + c2];
                    const uint2 w6 = e2[(size_t)tb.z * EMB4 + c2];
                    const uint2 w7 = e2[(size_t)tb.w * EMB4 + c2];
                    C += (bf4up(w0) + bf4up(w1)) + (bf4up(w2) + bf4up(w3));
                    D += (bf4up(w4) + bf4up(w5)) + (bf4up(w6) + bf4up(w7));
                }
            }
            for (; i + 4 <= n; i += 4) {
                const int4 t4 = *(const int4*)&toks[wave][i];
                const uint2 u0 = e2[(size_t)t4.x * EMB4 + lane];
                const uint2 u1 = e2[(size_t)t4.y * EMB4 + lane];
                const uint2 u2 = e2[(size_t)t4.z * EMB4 + lane];
                const uint2 u3 = e2[(size_t)t4.w * EMB4 + lane];
                A += bf4up(u0) + bf4up(u1);
                B += bf4up(u2) + bf4up(u3);
                if (two) {
                    C += bf4up(e2[(size_t)t4.x * EMB4 + c2]) + bf4up(e2[(size_t)t4.y * EMB4 + c2]);
                    D += bf4up(e2[(size_t)t4.z * EMB4 + c2]) + bf4up(e2[(size_t)t4.w * EMB4 + c2]);
                }
            }
            for (; i < n; ++i) {
                const int tk = toks[wave][i];
                A += bf4up(e2[(size_t)tk * EMB4 + lane]);
                if (two) C += bf4up(e2[(size_t)tk * EMB4 + c2]);
            }
            A += B;
            C += D;

            f32x4* dst = (f32x4*)(partial + ((size_t)x * BATCH + b) * EMB);
            __builtin_nontemporal_store(A, dst + lane);
            if (two) __builtin_nontemporal_store(C, dst + c2);
        }
    }
}

// ---------------- Kernel 3: fused combine + fc1 + relu + fc2 -----------------
template<int NXT>
__global__ __launch_bounds__(512) void mlp_kernel(
    const float* __restrict__ partial, // [NXT, BATCH, EMB]
    const int* __restrict__ lengths,   // [BATCH]
    const float* __restrict__ W1,      // [EMB, HIDDEN]
    const float* __restrict__ b1,      // [HIDDEN]
    const float* __restrict__ W2,      // [HIDDEN, 2]
    const float* __restrict__ b2,      // [2]
    float* __restrict__ out)           // [BATCH, 2]
{
    __shared__ f32x4 pQ[GMLP / 4][EMB];    // 9.6 KB
    __shared__ float hsh[GMLP][HIDDEN];    // 16 KB

    const int b0  = blockIdx.x * GMLP;
    const int tid = threadIdx.x;

    float* pQf = (float*)pQ;
    for (int i = tid; i < EMB * GMLP; i += 512) {
        const int g = i / EMB;
        const int e = i - g * EMB;
        float s = 0.f;
#pragma unroll
        for (int xx = 0; xx < NXT; ++xx)
            s += __builtin_nontemporal_load(
                     partial + ((size_t)xx * BATCH + b0 + g) * EMB + e);
        pQf[((g >> 2) * EMB + e) * 4 + (g & 3)] = s / (float)lengths[b0 + g];
    }
    __syncthreads();

    const int j = tid;                     // HIDDEN == blockDim
    const float bias = b1[j];
    f32x4 acc0 = {bias, bias, bias, bias};
    f32x4 acc1 = acc0;

#pragma unroll 10
    for (int e = 0; e < EMB; ++e) {
        const float w = W1[(size_t)e * HIDDEN + j];
        acc0 += pQ[0][e] * w;
        acc1 += pQ[1][e] * w;
    }
    hsh[0][j] = fmaxf(acc0.x, 0.f);
    hsh[1][j] = fmaxf(acc0.y, 0.f);
    hsh[2][j] = fmaxf(acc0.z, 0.f);
    hsh[3][j] = fmaxf(acc0.w, 0.f);
    hsh[4][j] = fmaxf(acc1.x, 0.f);
    hsh[5][j] = fmaxf(acc1.y, 0.f);
    hsh[6][j] = fmaxf(acc1.z, 0.f);
    hsh[7][j] = fmaxf(acc1.w, 0.f);
    __syncthreads();

    const int w    = tid >> 6;             // 0..7 -> batch row
    const int lane = tid & 63;
    const f32x4* W2v = (const f32x4*)W2;
    float s0 = 0.f, s1 = 0.f;
#pragma unroll
    for (int q = 0; q < 2; ++q) {
        const int cc = lane + q * 64;
        const f32x4 hv = *(const f32x4*)&hsh[w][4 * cc];
        const f32x4 wA = W2v[2 * cc + 0];
        const f32x4 wB = W2v[2 * cc + 1];
        s0 += hv.x * wA.x + hv.y * wA.z + hv.z * wB.x + hv.w * wB.z;
        s1 += hv.x * wA.y + hv.y * wA.w + hv.z * wB.y + hv.w * wB.w;
    }
#pragma unroll
    for (int off = 32; off > 0; off >>= 1) {
        s0 += __shfl_down(s0, off);
        s1 += __shfl_down(s1, off);
    }
    if (lane == 0) {
        out[(b0 + w) * 2 + 0] = s0 + b2[0];
        out[(b0 + w) * 2 + 1] = s1 + b2[1];
    }
}

// ---------------- Fallback pool (tiny ws): naive f32 gather ------------------
__global__ __launch_bounds__(320) void naive_pool(
    const int* __restrict__ text, const int* __restrict__ lengths,
    const float* __restrict__ emb, float* __restrict__ pooled)
{
    __shared__ int toks[SEQ];
    const int b = blockIdx.x;
    const int len = lengths[b];
    for (int s = threadIdx.x; s < len; s += 320)
        toks[s] = text[(size_t)s * BATCH + b];
    __syncthreads();
    const int e = threadIdx.x;
    if (e < EMB) {
        float a = 0.f;
        for (int s = 0; s < len; ++s)
            a += emb[(size_t)toks[s] * EMB + e];
        pooled[(size_t)b * EMB + e] = a;   // mlp<1> divides by len
    }
}

extern "C" void kernel_launch(void* const* d_in, const int* in_sizes, int n_in,
                              void* d_out, int out_size, void* d_ws, size_t ws_size,
                              hipStream_t stream) {
    const int*   text    = (const int*)d_in[0];
    const int*   lengths = (const int*)d_in[1];
    const float* emb     = (const float*)d_in[2];
    const float* W1      = (const float*)d_in[3];
    const float* b1      = (const float*)d_in[4];
    const float* W2      = (const float*)d_in[5];
    const float* b2      = (const float*)d_in[6];
    float*       out     = (float*)d_out;

    char* ws = (char*)d_ws;
    const size_t btokBytes = (size_t)BATCH * SEQ * sizeof(int);            // 2 MB
    const size_t boffBytes = (size_t)BATCH * (NBUK + 1) * sizeof(int);     // 132 KB
    const size_t tickBytes = (size_t)NX * TSTR * sizeof(int);              // 1 KB
    const size_t ebfBytes  = (size_t)VOCAB * EMB * sizeof(unsigned short); // 30 MB
    const size_t poolBytes = (size_t)BATCH * EMB * sizeof(float);          // 1.2 MB

    int* btok = (int*)ws;
    int* boff = (int*)(ws + btokBytes);
    size_t off = btokBytes + boffBytes;
    off = (off + 127) & ~(size_t)127;
    int* tickets = (int*)(ws + off);
    off += tickBytes;
    unsigned short* ebf = (unsigned short*)(ws + off);
    float* partial = (float*)(ws + off + ebfBytes);

    const size_t need = off + ebfBytes + (size_t)NX * poolBytes;   // ~42 MB

    if (ws_size >= need) {
        prep_kernel<<<256 + NCONV, 256, 0, stream>>>(
            text, lengths, emb, btok, boff, ebf, tickets, 1);
        pool_kernel<<<NX * NQ, 256, 0, stream>>>(btok, boff, ebf, partial, tickets);
        mlp_kernel<8><<<BATCH / GMLP, 512, 0, stream>>>(
            partial, lengths, W1, b1, W2, b2, out);
    } else {
        float* pooled = (float*)ws;    // [BATCH, EMB], 1.2 MB
        naive_pool<<<BATCH, 320, 0, stream>>>(text, lengths, emb, pooled);
        mlp_kernel<1><<<BATCH / GMLP, 512, 0, stream>>>(
            pooled, lengths, W1, b1, W2, b2, out);
    }
}

// Round 15
// 79.467 us; speedup vs baseline: 1.0540x; 1.0540x over previous
//
#include <hip/hip_runtime.h>
#include <hip/hip_cooperative_groups.h>

namespace cg = cooperative_groups;

typedef float f32x4 __attribute__((ext_vector_type(4)));

constexpr int EMB    = 300;
constexpr int EMB4   = 75;     // 8-B bf16 chunks per row
constexpr int HIDDEN = 512;
constexpr int SEQ    = 512;
constexpr int BATCH  = 1024;
constexpr int VOCAB  = 50000;
constexpr int NBUK   = 32;     // vocab buckets
constexpr int BDIV   = 1563;   // ceil(50000/32)
constexpr int NX     = 8;      // vocab slots (NJ=4 buckets each)
constexpr int GMLP   = 8;      // batches per mlp block
constexpr int NBLK   = 2048;   // fused grid: 8 blocks/CU x 256 CUs
constexpr int NCONVF = NBLK - 256;  // convert blocks in fused kernel
constexpr int NCONV  = 1792;   // convert blocks in fallback prep
constexpr int ELEM4  = VOCAB * EMB / 4;
constexpr int MLPB   = BATCH / GMLP;   // 128 mlp blocks

__device__ __forceinline__ unsigned short f2bf(float x) {   // RNE f32->bf16
    unsigned u = __float_as_uint(x);
    u += 0x7fffu + ((u >> 16) & 1u);
    return (unsigned short)(u >> 16);
}

__device__ __forceinline__ f32x4 bf4up(uint2 u) {   // 4 bf16 -> f32x4
    f32x4 r;
    r.x = __uint_as_float(u.x << 16);
    r.y = __uint_as_float(u.x & 0xffff0000u);
    r.z = __uint_as_float(u.y << 16);
    r.w = __uint_as_float(u.y & 0xffff0000u);
    return r;
}

__device__ __forceinline__ f32x4 relu4(f32x4 v) {
    v.x = fmaxf(v.x, 0.f); v.y = fmaxf(v.y, 0.f);
    v.z = fmaxf(v.z, 0.f); v.w = fmaxf(v.w, 0.f);
    return v;
}

// LDS union so the fused kernel's footprint is max, not sum (12.5 KB -> 8 blk/CU)
union SharedU {
    struct { int4 tstage[SEQ]; int hist[4][8][NBUK + 2]; } bz;  // 12544 B
    struct { int toks[4][SEQ]; } pool;                          // 8192 B
    struct { f32x4 pQ[GMLP / 4][EMB]; f32x4 red[4][4]; } mlp;   // 9856 B
};

// ---------------- device phase: bucketize 4 batches (1/wave) -----------------
__device__ void bucketize_phase(SharedU& sh, int bid, int tid,
                                const int* __restrict__ text,
                                const int* __restrict__ lengths,
                                int* __restrict__ btok,
                                int* __restrict__ boff)
{
    const int wave = tid >> 6;
    const int lane = tid & 63;
    const int b0   = bid * 4;
    const int b    = b0 + wave;
    const int len  = lengths[b];
    const unsigned long long lt = (1ull << lane) - 1ull;

    for (int s = tid; s < SEQ; s += 256)
        sh.bz.tstage[s] = *(const int4*)&text[(size_t)s * BATCH + b0];
    for (int i = tid; i < 4 * 8 * (NBUK + 2); i += 256)
        ((int*)sh.bz.hist)[i] = 0;
    __syncthreads();

    int tokv[8], kv[8], rkv[8];
#pragma unroll
    for (int c = 0; c < 8; ++c) {
        const int s      = c * 64 + lane;
        const bool valid = s < len;
        const int tok = valid ? ((const int*)&sh.bz.tstage[s])[wave] : 0;
        const int k   = valid ? tok / BDIV : NBUK;
        unsigned long long mm = ~0ull;
#pragma unroll
        for (int bit = 0; bit < 6; ++bit) {
            const unsigned long long bl = __ballot((k >> bit) & 1);
            mm &= ((k >> bit) & 1) ? bl : ~bl;
        }
        const int rk = __popcll(mm & lt);
        tokv[c] = tok; kv[c] = k; rkv[c] = rk;
        if (valid && rk == 0) sh.bz.hist[wave][c][k] = __popcll(mm);
    }
    __syncthreads();

    int tot = 0;
    if (lane < NBUK) {
#pragma unroll
        for (int c = 0; c < 8; ++c) {
            const int t = sh.bz.hist[wave][c][lane];
            sh.bz.hist[wave][c][lane] = tot;
            tot += t;
        }
    }
    int incl = tot;
#pragma unroll
    for (int off = 1; off < 32; off <<= 1) {
        const int v = __shfl_up(incl, off);
        if (lane >= off && lane < NBUK) incl += v;
    }
    const int excl = incl - tot;
    if (lane < NBUK)      boff[b * (NBUK + 1) + lane] = excl;
    if (lane == NBUK - 1) boff[b * (NBUK + 1) + NBUK] = incl;
    __syncthreads();

#pragma unroll
    for (int c = 0; c < 8; ++c) {
        const int s  = c * 64 + lane;
        const int k  = kv[c];
        const int bb = __shfl(excl, k);
        const int pos = bb + sh.bz.hist[wave][c][k] + rkv[c];
        if (s < len) btok[(size_t)b * SEQ + pos] = tokv[c];
    }
}

// ---------------- device phase: pool one (batch, slot) per wave --------------
__device__ void pool_phase(SharedU& sh, int bid, int tid,
                           const int* __restrict__ btok,
                           const int* __restrict__ boff,
                           const unsigned short* __restrict__ ebf,
                           float* __restrict__ partial)
{
    const int wave = tid >> 6;
    const int lane = tid & 63;
    const int x    = bid & (NX - 1);
    const int b    = (bid >> 3) * 4 + wave;
    const int NJ   = NBUK / NX;

    const int lo = boff[b * (NBUK + 1) + x * NJ];
    const int hi = boff[b * (NBUK + 1) + x * NJ + NJ];
    const int n  = hi - lo;

    for (int t = lane; t < n; t += 64)
        sh.pool.toks[wave][t] = btok[(size_t)b * SEQ + lo + t];
    // no barrier: same-wave LDS ordering handled by lgkmcnt

    const uint2* e2 = (const uint2*)ebf;
    const bool two  = lane < (EMB4 - 64);
    const int  c2   = 64 + lane;

    f32x4 A = {0.f, 0.f, 0.f, 0.f};
    f32x4 B = A, C = A;
    int i = 0;
    for (; i + 4 <= n; i += 4) {
        const int4 t4 = *(const int4*)&sh.pool.toks[wave][i];
        const uint2 u0 = e2[(size_t)t4.x * EMB4 + lane];
        const uint2 u1 = e2[(size_t)t4.y * EMB4 + lane];
        const uint2 u2 = e2[(size_t)t4.z * EMB4 + lane];
        const uint2 u3 = e2[(size_t)t4.w * EMB4 + lane];
        A += bf4up(u0) + bf4up(u1);
        B += bf4up(u2) + bf4up(u3);
        if (two) {
            const uint2 w0 = e2[(size_t)t4.x * EMB4 + c2];
            const uint2 w1 = e2[(size_t)t4.y * EMB4 + c2];
            const uint2 w2 = e2[(size_t)t4.z * EMB4 + c2];
            const uint2 w3 = e2[(size_t)t4.w * EMB4 + c2];
            C += (bf4up(w0) + bf4up(w1)) + (bf4up(w2) + bf4up(w3));
        }
    }
    for (; i < n; ++i) {
        const int tk = sh.pool.toks[wave][i];
        A += bf4up(e2[(size_t)tk * EMB4 + lane]);
        if (two) C += bf4up(e2[(size_t)tk * EMB4 + c2]);
    }
    A += B;

    f32x4* dst = (f32x4*)(partial + ((size_t)x * BATCH + b) * EMB);
    dst[lane] = A;
    if (two) dst[c2] = C;
}

// ---------------- device phase: combine + fc1 + relu + fc2 (256 thr) ---------
__device__ void mlp_phase(SharedU& sh, int bid, int tid,
                          const float* __restrict__ partial,
                          const int* __restrict__ lengths,
                          const float* __restrict__ W1,
                          const float* __restrict__ b1,
                          const float* __restrict__ W2,
                          const float* __restrict__ b2,
                          float* __restrict__ out)
{
    const int b0 = bid * GMLP;

    float* pQf = (float*)sh.mlp.pQ;
    for (int i = tid; i < EMB * GMLP; i += 256) {
        const int g = i / EMB;
        const int e = i - g * EMB;
        float s = 0.f;
#pragma unroll
        for (int xx = 0; xx < NX; ++xx)
            s += partial[((size_t)xx * BATCH + b0 + g) * EMB + e];
        pQf[((g >> 2) * EMB + e) * 4 + (g & 3)] = s / (float)lengths[b0 + g];
    }
    __syncthreads();

    // fc1: thread owns cols j0=tid, j1=tid+256; quads q=0 (b0..b0+3), q=1 (+4..7)
    const int j0 = tid, j1 = tid + 256;
    const float bi0 = b1[j0], bi1 = b1[j1];
    f32x4 a00 = {bi0, bi0, bi0, bi0}, a01 = a00;
    f32x4 a10 = {bi1, bi1, bi1, bi1}, a11 = a10;
#pragma unroll 4
    for (int e = 0; e < EMB; ++e) {
        const float w0 = W1[(size_t)e * HIDDEN + j0];
        const float w1 = W1[(size_t)e * HIDDEN + j1];
        const f32x4 p0 = sh.mlp.pQ[0][e];
        const f32x4 p1 = sh.mlp.pQ[1][e];
        a00 += p0 * w0; a01 += p1 * w0;
        a10 += p0 * w1; a11 += p1 * w1;
    }
    a00 = relu4(a00); a01 = relu4(a01);
    a10 = relu4(a10); a11 = relu4(a11);

    // fc2 partials: s{comp}{quad}
    const float w2a0 = W2[j0 * 2 + 0], w2a1 = W2[j0 * 2 + 1];
    const float w2b0 = W2[j1 * 2 + 0], w2b1 = W2[j1 * 2 + 1];
    f32x4 s00 = a00 * w2a0 + a10 * w2b0;
    f32x4 s01 = a01 * w2a0 + a11 * w2b0;
    f32x4 s10 = a00 * w2a1 + a10 * w2b1;
    f32x4 s11 = a01 * w2a1 + a11 * w2b1;

#define WRED(v)                                                     \
    for (int o = 32; o > 0; o >>= 1) {                              \
        v.x += __shfl_down(v.x, o); v.y += __shfl_down(v.y, o);     \
        v.z += __shfl_down(v.z, o); v.w += __shfl_down(v.w, o);     \
    }
    WRED(s00) WRED(s01) WRED(s10) WRED(s11)
#undef WRED

    const int wv = tid >> 6, ln = tid & 63;
    if (ln == 0) {
        sh.mlp.red[wv][0] = s00; sh.mlp.red[wv][1] = s01;
        sh.mlp.red[wv][2] = s10; sh.mlp.red[wv][3] = s11;
    }
    __syncthreads();
    if (tid == 0) {
        f32x4 t0 = sh.mlp.red[0][0] + sh.mlp.red[1][0] + sh.mlp.red[2][0] + sh.mlp.red[3][0];
        f32x4 t1 = sh.mlp.red[0][1] + sh.mlp.red[1][1] + sh.mlp.red[2][1] + sh.mlp.red[3][1];
        f32x4 t2 = sh.mlp.red[0][2] + sh.mlp.red[1][2] + sh.mlp.red[2][2] + sh.mlp.red[3][2];
        f32x4 t3 = sh.mlp.red[0][3] + sh.mlp.red[1][3] + sh.mlp.red[2][3] + sh.mlp.red[3][3];
        const float z0 = b2[0], z1 = b2[1];
        out[(b0 + 0) * 2 + 0] = t0.x + z0; out[(b0 + 0) * 2 + 1] = t2.x + z1;
        out[(b0 + 1) * 2 + 0] = t0.y + z0; out[(b0 + 1) * 2 + 1] = t2.y + z1;
        out[(b0 + 2) * 2 + 0] = t0.z + z0; out[(b0 + 2) * 2 + 1] = t2.z + z1;
        out[(b0 + 3) * 2 + 0] = t0.w + z0; out[(b0 + 3) * 2 + 1] = t2.w + z1;
        out[(b0 + 4) * 2 + 0] = t1.x + z0; out[(b0 + 4) * 2 + 1] = t3.x + z1;
        out[(b0 + 5) * 2 + 0] = t1.y + z0; out[(b0 + 5) * 2 + 1] = t3.y + z1;
        out[(b0 + 6) * 2 + 0] = t1.z + z0; out[(b0 + 6) * 2 + 1] = t3.z + z1;
        out[(b0 + 7) * 2 + 0] = t1.w + z0; out[(b0 + 7) * 2 + 1] = t3.w + z1;
    }
}

// ---------------- fused cooperative kernel -----------------------------------
__global__ __launch_bounds__(256, 8) void fused_kernel(
    const int* text, const int* lengths, const float* emb,
    const float* W1, const float* b1, const float* W2, const float* b2,
    float* out, int* btok, int* boff, unsigned short* ebf, float* partial)
{
    __shared__ SharedU sh;
    const int bid = blockIdx.x;
    const int tid = threadIdx.x;

    // Phase 1: bucketize (blocks 0..255) || f32->bf16 convert (blocks 256..2047)
    if (bid < 256) {
        bucketize_phase(sh, bid, tid, text, lengths, btok, boff);
    } else {
        const float4* src = (const float4*)emb;
        ushort4*      dst = (ushort4*)ebf;
        const int gtid = (bid - 256) * 256 + tid;
        for (int i = gtid; i < ELEM4; i += NCONVF * 256) {
            const float4 v = src[i];
            ushort4 o;
            o.x = f2bf(v.x); o.y = f2bf(v.y);
            o.z = f2bf(v.z); o.w = f2bf(v.w);
            dst[i] = o;
        }
    }
    cg::this_grid().sync();

    // Phase 2: pool (all 2048 blocks)
    pool_phase(sh, bid, tid, btok, boff, ebf, partial);
    cg::this_grid().sync();

    // Phase 3: mlp (blocks 0..127)
    if (bid < MLPB)
        mlp_phase(sh, bid, tid, partial, lengths, W1, b1, W2, b2, out);
}

// ================= fallback 3-kernel pipeline (R12, proven 63 µs) ============
__global__ __launch_bounds__(256) void prep_kernel(
    const int* __restrict__ text, const int* __restrict__ lengths,
    const float* __restrict__ emb, int* __restrict__ btok,
    int* __restrict__ boff, unsigned short* __restrict__ ebf)
{
    __shared__ SharedU sh;
    const int tid = threadIdx.x;
    if (blockIdx.x >= 256) {
        const float4* src = (const float4*)emb;
        ushort4*      dst = (ushort4*)ebf;
        const int gtid = (blockIdx.x - 256) * 256 + tid;
        for (int i = gtid; i < ELEM4; i += NCONV * 256) {
            const float4 v = src[i];
            ushort4 o;
            o.x = f2bf(v.x); o.y = f2bf(v.y);
            o.z = f2bf(v.z); o.w = f2bf(v.w);
            dst[i] = o;
        }
        return;
    }
    bucketize_phase(sh, blockIdx.x, tid, text, lengths, btok, boff);
}

__global__ __launch_bounds__(256) void pool_kernel(
    const int* __restrict__ btok, const int* __restrict__ boff,
    const unsigned short* __restrict__ ebf, float* __restrict__ partial)
{
    __shared__ SharedU sh;
    pool_phase(sh, blockIdx.x, threadIdx.x, btok, boff, ebf, partial);
}

__global__ __launch_bounds__(256) void mlp_kernel(
    const float* __restrict__ partial, const int* __restrict__ lengths,
    const float* __restrict__ W1, const float* __restrict__ b1,
    const float* __restrict__ W2, const float* __restrict__ b2,
    float* __restrict__ out)
{
    __shared__ SharedU sh;
    mlp_phase(sh, blockIdx.x, threadIdx.x, partial, lengths, W1, b1, W2, b2, out);
}

// -------- tiny-ws fallback: naive f32 pool + direct mlp ----------------------
__global__ __launch_bounds__(320) void naive_pool(
    const int* __restrict__ text, const int* __restrict__ lengths,
    const float* __restrict__ emb, float* __restrict__ pooled)
{
    __shared__ int toks[SEQ];
    const int b = blockIdx.x;
    const int len = lengths[b];
    for (int s = threadIdx.x; s < len; s += 320)
        toks[s] = text[(size_t)s * BATCH + b];
    __syncthreads();
    const int e = threadIdx.x;
    if (e < EMB) {
        float a = 0.f;
        for (int s = 0; s < len; ++s)
            a += emb[(size_t)toks[s] * EMB + e];
        pooled[(size_t)b * EMB + e] = a;
    }
}

__global__ __launch_bounds__(256) void mlp1_kernel(
    const float* __restrict__ pooled, const int* __restrict__ lengths,
    const float* __restrict__ W1, const float* __restrict__ b1,
    const float* __restrict__ W2, const float* __restrict__ b2,
    float* __restrict__ out)
{
    __shared__ SharedU sh;
    const int b0  = blockIdx.x * GMLP;
    const int tid = threadIdx.x;
    float* pQf = (float*)sh.mlp.pQ;
    for (int i = tid; i < EMB * GMLP; i += 256) {
        const int g = i / EMB;
        const int e = i - g * EMB;
        pQf[((g >> 2) * EMB + e) * 4 + (g & 3)] =
            pooled[(size_t)(b0 + g) * EMB + e] / (float)lengths[b0 + g];
    }
    __syncthreads();
    // reuse fc1/fc2 from mlp_phase by inlining the remainder via a second pass:
    const int j0 = tid, j1 = tid + 256;
    const float bi0 = b1[j0], bi1 = b1[j1];
    f32x4 a00 = {bi0, bi0, bi0, bi0}, a01 = a00;
    f32x4 a10 = {bi1, bi1, bi1, bi1}, a11 = a10;
#pragma unroll 4
    for (int e = 0; e < EMB; ++e) {
        const float w0 = W1[(size_t)e * HIDDEN + j0];
        const float w1 = W1[(size_t)e * HIDDEN + j1];
        const f32x4 p0 = sh.mlp.pQ[0][e];
        const f32x4 p1 = sh.mlp.pQ[1][e];
        a00 += p0 * w0; a01 += p1 * w0;
        a10 += p0 * w1; a11 += p1 * w1;
    }
    a00 = relu4(a00); a01 = relu4(a01);
    a10 = relu4(a10); a11 = relu4(a11);
    const float w2a0 = W2[j0 * 2 + 0], w2a1 = W2[j0 * 2 + 1];
    const float w2b0 = W2[j1 * 2 + 0], w2b1 = W2[j1 * 2 + 1];
    f32x4 s00 = a00 * w2a0 + a10 * w2b0;
    f32x4 s01 = a01 * w2a0 + a11 * w2b0;
    f32x4 s10 = a00 * w2a1 + a10 * w2b1;
    f32x4 s11 = a01 * w2a1 + a11 * w2b1;
#define WRED(v)                                                     \
    for (int o = 32; o > 0; o >>= 1) {                              \
        v.x += __shfl_down(v.x, o); v.y += __shfl_down(v.y, o);     \
        v.z += __shfl_down(v.z, o); v.w += __shfl_down(v.w, o);     \
    }
    WRED(s00) WRED(s01) WRED(s10) WRED(s11)
#undef WRED
    const int wv = tid >> 6, ln = tid & 63;
    if (ln == 0) {
        sh.mlp.red[wv][0] = s00; sh.mlp.red[wv][1] = s01;
        sh.mlp.red[wv][2] = s10; sh.mlp.red[wv][3] = s11;
    }
    __syncthreads();
    if (tid == 0) {
        f32x4 t0 = sh.mlp.red[0][0] + sh.mlp.red[1][0] + sh.mlp.red[2][0] + sh.mlp.red[3][0];
        f32x4 t1 = sh.mlp.red[0][1] + sh.mlp.red[1][1] + sh.mlp.red[2][1] + sh.mlp.red[3][1];
        f32x4 t2 = sh.mlp.red[0][2] + sh.mlp.red[1][2] + sh.mlp.red[2][2] + sh.mlp.red[3][2];
        f32x4 t3 = sh.mlp.red[0][3] + sh.mlp.red[1][3] + sh.mlp.red[2][3] + sh.mlp.red[3][3];
        const float z0 = b2[0], z1 = b2[1];
        out[(b0 + 0) * 2 + 0] = t0.x + z0; out[(b0 + 0) * 2 + 1] = t2.x + z1;
        out[(b0 + 1) * 2 + 0] = t0.y + z0; out[(b0 + 1) * 2 + 1] = t2.y + z1;
        out[(b0 + 2) * 2 + 0] = t0.z + z0; out[(b0 + 2) * 2 + 1] = t2.z + z1;
        out[(b0 + 3) * 2 + 0] = t0.w + z0; out[(b0 + 3) * 2 + 1] = t2.w + z1;
        out[(b0 + 4) * 2 + 0] = t1.x + z0; out[(b0 + 4) * 2 + 1] = t3.x + z1;
        out[(b0 + 5) * 2 + 0] = t1.y + z0; out[(b0 + 5) * 2 + 1] = t3.y + z1;
        out[(b0 + 6) * 2 + 0] = t1.z + z0; out[(b0 + 6) * 2 + 1] = t3.z + z1;
        out[(b0 + 7) * 2 + 0] = t1.w + z0; out[(b0 + 7) * 2 + 1] = t3.w + z1;
    }
}

extern "C" void kernel_launch(void* const* d_in, const int* in_sizes, int n_in,
                              void* d_out, int out_size, void* d_ws, size_t ws_size,
                              hipStream_t stream) {
    const int*   text    = (const int*)d_in[0];
    const int*   lengths = (const int*)d_in[1];
    const float* emb     = (const float*)d_in[2];
    const float* W1      = (const float*)d_in[3];
    const float* b1      = (const float*)d_in[4];
    const float* W2      = (const float*)d_in[5];
    const float* b2      = (const float*)d_in[6];
    float*       out     = (float*)d_out;

    char* ws = (char*)d_ws;
    const size_t btokBytes = (size_t)BATCH * SEQ * sizeof(int);            // 2 MB
    const size_t boffBytes = (size_t)BATCH * (NBUK + 1) * sizeof(int);     // 132 KB
    const size_t ebfBytes  = (size_t)VOCAB * EMB * sizeof(unsigned short); // 30 MB
    const size_t poolBytes = (size_t)BATCH * EMB * sizeof(float);          // 1.2 MB

    int* btok = (int*)ws;
    int* boff = (int*)(ws + btokBytes);
    size_t off = btokBytes + boffBytes;
    off = (off + 127) & ~(size_t)127;
    unsigned short* ebf = (unsigned short*)(ws + off);
    float* partial = (float*)(ws + off + ebfBytes);
    const size_t need = off + ebfBytes + (size_t)NX * poolBytes;   // ~42 MB

    if (ws_size < need) {
        float* pooled = (float*)ws;
        naive_pool<<<BATCH, 320, 0, stream>>>(text, lengths, emb, pooled);
        mlp1_kernel<<<BATCH / GMLP, 256, 0, stream>>>(pooled, lengths, W1, b1, W2, b2, out);
        return;
    }

    // Decide cooperative path (host-side queries only: graph-capture safe,
    // deterministic per device).
    int dev = 0;
    hipGetDevice(&dev);
    int coop = 0, nCU = 0, maxb = 0;
    hipDeviceGetAttribute(&coop, hipDeviceAttributeCooperativeLaunch, dev);
    hipDeviceGetAttribute(&nCU, hipDeviceAttributeMultiprocessorCount, dev);
    hipOccupancyMaxActiveBlocksPerMultiprocessor(&maxb, fused_kernel, 256, 0);

    if (coop && (long)maxb * nCU >= NBLK) {
        void* args[] = {(void*)&text, (void*)&lengths, (void*)&emb,
                        (void*)&W1, (void*)&b1, (void*)&W2, (void*)&b2,
                        (void*)&out, (void*)&btok, (void*)&boff,
                        (void*)&ebf, (void*)&partial};
        hipLaunchCooperativeKernel((void*)fused_kernel, dim3(NBLK), dim3(256),
                                   args, 0, stream);
    } else {
        prep_kernel<<<256 + NCONV, 256, 0, stream>>>(text, lengths, emb, btok, boff, ebf);
        pool_kernel<<<NX * (BATCH / 4), 256, 0, stream>>>(btok, boff, ebf, partial);
        mlp_kernel<<<MLPB, 256, 0, stream>>>(partial, lengths, W1, b1, W2, b2, out);
    }
}

// Round 16
// 61.977 us; speedup vs baseline: 1.3515x; 1.2822x over previous
//
#include <hip/hip_runtime.h>

typedef float f32x4 __attribute__((ext_vector_type(4)));

constexpr int EMB    = 300;
constexpr int EMB4   = 75;     // EMB/4 (8-B bf16 chunks per row)
constexpr int HIDDEN = 512;
constexpr int SEQ    = 512;
constexpr int BATCH  = 1024;
constexpr int VOCAB  = 50000;
constexpr int NBUK   = 32;     // vocab buckets
constexpr int BDIV   = 1563;   // ceil(50000/32)
constexpr int PB     = 4;      // batches per pool block
constexpr int GMLP   = 8;      // batches per mlp block
constexpr int NCONV  = 1792;   // convert blocks inside prep (256+1792 = 2048 total)
constexpr int ELEM4  = VOCAB * EMB / 4;   // 3,750,000 float4s in emb

__device__ __forceinline__ unsigned short f2bf(float x) {   // RNE f32->bf16
    unsigned u = __float_as_uint(x);
    u += 0x7fffu + ((u >> 16) & 1u);
    return (unsigned short)(u >> 16);
}

__device__ __forceinline__ f32x4 bf4up(uint2 u) {   // 4 bf16 -> f32x4
    f32x4 r;
    r.x = __uint_as_float(u.x << 16);
    r.y = __uint_as_float(u.x & 0xffff0000u);
    r.z = __uint_as_float(u.y << 16);
    r.w = __uint_as_float(u.y & 0xffff0000u);
    return r;
}

// ---------------- Kernel 1: prep = bucketize (blocks 0..255) + f32->bf16 -----
// Blocks 0..255: bucketize v2 (verified since R9, bitwise-stable output).
// Blocks 256..2047: grid-stride convert of emb (60 MB read, 30 MB write).
__global__ __launch_bounds__(256) void prep_kernel(
    const int* __restrict__ text,      // [SEQ, BATCH]
    const int* __restrict__ lengths,   // [BATCH]
    const float* __restrict__ emb,     // [VOCAB, EMB]
    int* __restrict__ btok,            // [BATCH, SEQ]
    int* __restrict__ boff,            // [BATCH, NBUK+1]
    unsigned short* __restrict__ ebf,  // [VOCAB, EMB] bf16
    int doConv)
{
    __shared__ int4 tstage[SEQ];           // 8 KB
    __shared__ int  hist[4][8][NBUK + 2];

    const int tid = threadIdx.x;

    if (blockIdx.x >= 256) {               // ---- convert lane ----
        if (!doConv) return;
        const float4* src = (const float4*)emb;
        ushort4*      dst = (ushort4*)ebf;
        const int gtid = (blockIdx.x - 256) * 256 + tid;
        for (int i = gtid; i < ELEM4; i += NCONV * 256) {
            const float4 v = src[i];
            ushort4 o;
            o.x = f2bf(v.x); o.y = f2bf(v.y);
            o.z = f2bf(v.z); o.w = f2bf(v.w);
            dst[i] = o;
        }
        return;
    }

    // ---- bucketize lane (4 waves = 4 batches) ----
    const int wave = tid >> 6;
    const int lane = tid & 63;
    const int b0   = blockIdx.x * 4;
    const int b    = b0 + wave;
    const int len  = lengths[b];
    const unsigned long long lt = (1ull << lane) - 1ull;

    for (int s = tid; s < SEQ; s += 256)
        tstage[s] = *(const int4*)&text[(size_t)s * BATCH + b0];
    for (int i = tid; i < 4 * 8 * (NBUK + 2); i += 256)
        ((int*)hist)[i] = 0;
    __syncthreads();

    int tokv[8], kv[8], rkv[8];
#pragma unroll
    for (int c = 0; c < 8; ++c) {
        const int s      = c * 64 + lane;
        const bool valid = s < len;
        const int tok = valid ? ((const int*)&tstage[s])[wave] : 0;
        const int k   = valid ? tok / BDIV : NBUK;
        unsigned long long mm = ~0ull;
#pragma unroll
        for (int bit = 0; bit < 6; ++bit) {
            const unsigned long long bl = __ballot((k >> bit) & 1);
            mm &= ((k >> bit) & 1) ? bl : ~bl;
        }
        const int rk = __popcll(mm & lt);
        tokv[c] = tok; kv[c] = k; rkv[c] = rk;
        if (valid && rk == 0) hist[wave][c][k] = __popcll(mm);
    }
    __syncthreads();

    int tot = 0;
    if (lane < NBUK) {
#pragma unroll
        for (int c = 0; c < 8; ++c) {
            const int t = hist[wave][c][lane];
            hist[wave][c][lane] = tot;
            tot += t;
        }
    }
    int incl = tot;
#pragma unroll
    for (int off = 1; off < 32; off <<= 1) {
        const int v = __shfl_up(incl, off);
        if (lane >= off && lane < NBUK) incl += v;
    }
    const int excl = incl - tot;
    if (lane < NBUK)      boff[b * (NBUK + 1) + lane] = excl;
    if (lane == NBUK - 1) boff[b * (NBUK + 1) + NBUK] = incl;
    __syncthreads();

#pragma unroll
    for (int c = 0; c < 8; ++c) {
        const int s  = c * 64 + lane;
        const int k  = kv[c];
        const int bb = __shfl(excl, k);
        const int pos = bb + hist[wave][c][k] + rkv[c];
        if (s < len) btok[(size_t)b * SEQ + pos] = tokv[c];
    }
}

// ---------------- Kernel 2: pool (R6/R9 structure; bf16 or f32 rows) ---------
// Slot x owns contiguous buckets [x*NJ,(x+1)*NJ) (best measured locality).
// BF: lane c reads 8 B (4 bf16) of the 600-B row -> half the bytes AND half
// the cache lines per row vs f32.
template<bool BF>
__global__ __launch_bounds__(320) void pool_kernel(
    const int* __restrict__ btok,      // [BATCH, SEQ] bucket-grouped
    const int* __restrict__ boff,      // [BATCH, NBUK+1]
    const float* __restrict__ emb,     // [VOCAB, EMB] f32
    const unsigned short* __restrict__ ebf, // [VOCAB, EMB] bf16
    float* __restrict__ partial,       // [NX, BATCH, EMB]
    int NX)
{
    const int x  = blockIdx.x % NX;    // slot ~ XCD (round-robin dispatch)
    const int b0 = (blockIdx.x / NX) * PB;
    const int NJ = NBUK / NX;

    __shared__ int toks[PB][SEQ];
    __shared__ int seg[PB][2];

    if (threadIdx.x < PB) {
        const int b  = b0 + threadIdx.x;
        const int lo = boff[b * (NBUK + 1) + x * NJ];
        const int hi = boff[b * (NBUK + 1) + x * NJ + NJ];
        seg[threadIdx.x][0] = lo;
        seg[threadIdx.x][1] = hi - lo;
    }
    __syncthreads();

    for (int g = 0; g < PB; ++g) {
        const int lo = seg[g][0], n = seg[g][1];
        for (int t = threadIdx.x; t < n; t += 320)
            toks[g][t] = btok[(size_t)(b0 + g) * SEQ + lo + t];
    }
    __syncthreads();

    const int g = threadIdx.x / 80;
    const int c = threadIdx.x % 80;
    if (c < EMB4) {
        const int n = seg[g][1];
        f32x4 A = {0.f, 0.f, 0.f, 0.f};
        f32x4 B = A;
        int i = 0;
        if constexpr (BF) {
            const uint2* e2 = (const uint2*)ebf;   // row stride EMB4 uint2s
            for (; i + 4 <= n; i += 4) {
                const int4 t4 = *(const int4*)&toks[g][i];
                const uint2 u0 = e2[(size_t)t4.x * EMB4 + c];
                const uint2 u1 = e2[(size_t)t4.y * EMB4 + c];
                const uint2 u2 = e2[(size_t)t4.z * EMB4 + c];
                const uint2 u3 = e2[(size_t)t4.w * EMB4 + c];
                A += bf4up(u0) + bf4up(u1);
                B += bf4up(u2) + bf4up(u3);
            }
            for (; i < n; ++i)
                A += bf4up(e2[(size_t)toks[g][i] * EMB4 + c]);
        } else {
            const f32x4* e4 = (const f32x4*)emb;   // row stride EMB4 f32x4s
            for (; i + 4 <= n; i += 4) {
                const int4 t4 = *(const int4*)&toks[g][i];
                const f32x4 v0 = e4[(size_t)t4.x * EMB4 + c];
                const f32x4 v1 = e4[(size_t)t4.y * EMB4 + c];
                const f32x4 v2 = e4[(size_t)t4.z * EMB4 + c];
                const f32x4 v3 = e4[(size_t)t4.w * EMB4 + c];
                A += v0 + v1;
                B += v2 + v3;
            }
            for (; i < n; ++i)
                A += e4[(size_t)toks[g][i] * EMB4 + c];
        }
        A += B;
        ((f32x4*)(partial + ((size_t)x * BATCH + b0 + g) * EMB))[c] = A;
    }
}

// ---------------- Kernel 3: fused combine + fc1 + relu + fc2 -----------------
// 128 blocks x 512 thr; block owns 8 batches + full hidden dim. W1 (614 KB)
// is L2-resident -> 78 MB of L2 reads ~ few microseconds.
template<int NX>
__global__ __launch_bounds__(512) void mlp_kernel(
    const float* __restrict__ partial, // [NX, BATCH, EMB]
    const int* __restrict__ lengths,   // [BATCH]
    const float* __restrict__ W1,      // [EMB, HIDDEN]
    const float* __restrict__ b1,      // [HIDDEN]
    const float* __restrict__ W2,      // [HIDDEN, 2]
    const float* __restrict__ b2,      // [2]
    float* __restrict__ out)           // [BATCH, 2]
{
    __shared__ f32x4 pQ[GMLP / 4][EMB];    // 9.6 KB
    __shared__ float hsh[GMLP][HIDDEN];    // 16 KB

    const int b0  = blockIdx.x * GMLP;
    const int tid = threadIdx.x;

    float* pQf = (float*)pQ;
    for (int i = tid; i < EMB * GMLP; i += 512) {
        const int g = i / EMB;
        const int e = i - g * EMB;
        float s = 0.f;
#pragma unroll
        for (int xx = 0; xx < NX; ++xx)
            s += partial[((size_t)xx * BATCH + b0 + g) * EMB + e];
        pQf[((g >> 2) * EMB + e) * 4 + (g & 3)] = s / (float)lengths[b0 + g];
    }
    __syncthreads();

    const int j = tid;                     // HIDDEN == blockDim
    const float bias = b1[j];
    f32x4 acc0 = {bias, bias, bias, bias};
    f32x4 acc1 = acc0;

#pragma unroll 10
    for (int e = 0; e < EMB; ++e) {
        const float w = W1[(size_t)e * HIDDEN + j];
        acc0 += pQ[0][e] * w;
        acc1 += pQ[1][e] * w;
    }
    hsh[0][j] = fmaxf(acc0.x, 0.f);
    hsh[1][j] = fmaxf(acc0.y, 0.f);
    hsh[2][j] = fmaxf(acc0.z, 0.f);
    hsh[3][j] = fmaxf(acc0.w, 0.f);
    hsh[4][j] = fmaxf(acc1.x, 0.f);
    hsh[5][j] = fmaxf(acc1.y, 0.f);
    hsh[6][j] = fmaxf(acc1.z, 0.f);
    hsh[7][j] = fmaxf(acc1.w, 0.f);
    __syncthreads();

    const int w    = tid >> 6;             // 0..7 -> batch row
    const int lane = tid & 63;
    const f32x4* W2v = (const f32x4*)W2;
    float s0 = 0.f, s1 = 0.f;
#pragma unroll
    for (int q = 0; q < 2; ++q) {
        const int cc = lane + q * 64;      // f32x4 chunk of the h row
        const f32x4 hv = *(const f32x4*)&hsh[w][4 * cc];
        const f32x4 wA = W2v[2 * cc + 0];
        const f32x4 wB = W2v[2 * cc + 1];
        s0 += hv.x * wA.x + hv.y * wA.z + hv.z * wB.x + hv.w * wB.z;
        s1 += hv.x * wA.y + hv.y * wA.w + hv.z * wB.y + hv.w * wB.w;
    }
#pragma unroll
    for (int off = 32; off > 0; off >>= 1) {
        s0 += __shfl_down(s0, off);
        s1 += __shfl_down(s1, off);
    }
    if (lane == 0) {
        out[(b0 + w) * 2 + 0] = s0 + b2[0];
        out[(b0 + w) * 2 + 1] = s1 + b2[1];
    }
}

extern "C" void kernel_launch(void* const* d_in, const int* in_sizes, int n_in,
                              void* d_out, int out_size, void* d_ws, size_t ws_size,
                              hipStream_t stream) {
    const int*   text    = (const int*)d_in[0];
    const int*   lengths = (const int*)d_in[1];
    const float* emb     = (const float*)d_in[2];
    const float* W1      = (const float*)d_in[3];
    const float* b1      = (const float*)d_in[4];
    const float* W2      = (const float*)d_in[5];
    const float* b2      = (const float*)d_in[6];
    float*       out     = (float*)d_out;

    char* ws = (char*)d_ws;
    const size_t btokBytes = (size_t)BATCH * SEQ * sizeof(int);            // 2 MB
    const size_t boffBytes = (size_t)BATCH * (NBUK + 1) * sizeof(int);     // 132 KB
    const size_t ebfBytes  = (size_t)VOCAB * EMB * sizeof(unsigned short); // 30 MB
    const size_t poolBytes = (size_t)BATCH * EMB * sizeof(float);          // 1.2 MB

    int* btok = (int*)ws;
    int* boff = (int*)(ws + btokBytes);
    size_t off = btokBytes + boffBytes;
    off = (off + 63) & ~(size_t)63;
    unsigned short* ebf = (unsigned short*)(ws + off);

    const size_t fixedBF = off + ebfBytes;
    bool useBF = false;
    int NX = 1;
    float* partial;
    if (ws_size >= fixedBF + 2 * poolBytes) {
        useBF = true;
        partial = (float*)(ws + fixedBF);
        if      (ws_size >= fixedBF + 8 * poolBytes) NX = 8;
        else if (ws_size >= fixedBF + 4 * poolBytes) NX = 4;
        else                                         NX = 2;
    } else {
        partial = (float*)(ws + off);
        if      (ws_size >= off + 8 * poolBytes) NX = 8;
        else if (ws_size >= off + 4 * poolBytes) NX = 4;
        else if (ws_size >= off + 2 * poolBytes) NX = 2;
    }

    prep_kernel<<<useBF ? 256 + NCONV : 256, 256, 0, stream>>>(
        text, lengths, emb, btok, boff, ebf, useBF ? 1 : 0);

    if (useBF)
        pool_kernel<true><<<NX * (BATCH / PB), 320, 0, stream>>>(btok, boff, emb, ebf, partial, NX);
    else
        pool_kernel<false><<<NX * (BATCH / PB), 320, 0, stream>>>(btok, boff, emb, ebf, partial, NX);

    switch (NX) {
        case 8:  mlp_kernel<8><<<BATCH / GMLP, 512, 0, stream>>>(partial, lengths, W1, b1, W2, b2, out); break;
        case 4:  mlp_kernel<4><<<BATCH / GMLP, 512, 0, stream>>>(partial, lengths, W1, b1, W2, b2, out); break;
        case 2:  mlp_kernel<2><<<BATCH / GMLP, 512, 0, stream>>>(partial, lengths, W1, b1, W2, b2, out); break;
        default: mlp_kernel<1><<<BATCH / GMLP, 512, 0, stream>>>(partial, lengths, W1, b1, W2, b2, out); break;
    }
}